// Round 3
// baseline (351.757 us; speedup 1.0000x reference)
//
#include <hip/hip_runtime.h>
#include <hip/hip_bf16.h>

// Problem: B=2, S=2048, EMB=1024, H=16, D=64.
// Harness I/O dtype: fp32 (reference is jnp.float32); bf16-level tolerance
// permits internal bf16 MFMA. We convert fp32->bf16 once, run bf16 pipeline,
// write fp32 output.
#define BB   2
#define SS   2048
#define EMBD 1024
#define NH   16
#define HD   64
#define SCALE 0.125f     // 1/sqrt(64)
#define NEG_BIG (-1e30f) // finite "-inf" sentinel: exp paths can never make NaN

typedef __bf16 bf16;
typedef float  floatx4 __attribute__((ext_vector_type(4)));
typedef __bf16 bf16x4  __attribute__((ext_vector_type(4)));
typedef __bf16 bf16x8  __attribute__((ext_vector_type(8)));

typedef const __attribute__((address_space(1))) void* gas_ptr;
typedef __attribute__((address_space(3))) void*       las_ptr;

// async global->LDS, 16B per lane; LDS dest = wave-uniform base + lane*16
__device__ __forceinline__ void gl_lds16(const void* g, void* l) {
    __builtin_amdgcn_global_load_lds((gas_ptr)g, (las_ptr)l, 16, 0, 0);
}

// ---------------------------------------------------------------------------
// fp32 -> bf16 conversion for x tensors (4Mi els each) and W matrices (1Mi).
// grid: dim3(1024, 7), 256 thr. Grid-stride float4 -> bf16x4.
// ---------------------------------------------------------------------------
__global__ __launch_bounds__(256) void cvt_all(
    const float* __restrict__ xq, const float* __restrict__ xk,
    const float* __restrict__ xv, const float* __restrict__ Wq,
    const float* __restrict__ Wk, const float* __restrict__ Wv,
    const float* __restrict__ Wo, bf16* __restrict__ xqo,
    bf16* __restrict__ xko, bf16* __restrict__ xvo, bf16* __restrict__ Wqo,
    bf16* __restrict__ Wko, bf16* __restrict__ Wvo, bf16* __restrict__ Woo) {
    const int y = blockIdx.y;
    const float* src;
    bf16* dst;
    size_t n;
    const size_t NX = (size_t)BB * SS * EMBD;    // 4 Mi
    const size_t NW = (size_t)EMBD * EMBD;       // 1 Mi
    switch (y) {
        case 0: src = xq; dst = xqo; n = NX; break;
        case 1: src = xk; dst = xko; n = NX; break;
        case 2: src = xv; dst = xvo; n = NX; break;
        case 3: src = Wq; dst = Wqo; n = NW; break;
        case 4: src = Wk; dst = Wko; n = NW; break;
        case 5: src = Wv; dst = Wvo; n = NW; break;
        default: src = Wo; dst = Woo; n = NW; break;
    }
    const size_t stride = (size_t)gridDim.x * blockDim.x * 4;
    for (size_t i = ((size_t)blockIdx.x * blockDim.x + threadIdx.x) * 4;
         i < n; i += stride) {
        floatx4 v = *(const floatx4*)(src + i);
        bf16x4 o = {(bf16)v[0], (bf16)v[1], (bf16)v[2], (bf16)v[3]};
        *(bf16x4*)(dst + i) = o;
    }
}

// ---------------------------------------------------------------------------
// GEMM: out[m][n] = sum_k A[m][k] * W[n][k] + bias[n]      (x @ W.T + b)
// M=4096, N=1024, K=1024. 128x128 tile, BK=32, 4 waves, 4x4 16x16x32 frags.
// m97-exact staging: contiguous, unswizzled, global_load_lds width=16.
// A and W are bf16 (workspace copies). bias fp32.
// MODE 0: scatter bf16 to [B,H,S,D] (QKV).  MODE 1: fp32 linear [M][N].
// ---------------------------------------------------------------------------
template <int MODE>
__device__ __forceinline__ void gemm_body(const bf16* __restrict__ A,
                                          const bf16* __restrict__ W,
                                          const float* __restrict__ bias,
                                          void* __restrict__ Ov,
                                          int mBase, int nBase) {
    __shared__ __align__(16) bf16 As[128 * 32];
    __shared__ __align__(16) bf16 Bs[128 * 32];

    const int t = threadIdx.x;
    const int l = t & 63, w = t >> 6;
    const int lm = l & 15, lq = l >> 4;
    const int K = 1024;
    const int wm = (w >> 1) * 64, wn = (w & 1) * 64;

    const floatx4 zero = {0.f, 0.f, 0.f, 0.f};
    floatx4 acc[4][4];
#pragma unroll
    for (int i = 0; i < 4; i++)
#pragma unroll
        for (int j = 0; j < 4; j++) acc[i][j] = zero;

    for (int kb = 0; kb < K; kb += 32) {
        __syncthreads();
        // Stage A and B tiles: 128x32 each, contiguous (LDS chunk idx ==
        // global chunk idx) — exact m97 pattern, no swizzle.
#pragma unroll
        for (int i = 0; i < 2; i++) {
            int idx  = i * 256 + t;           // 0..511 lane-chunks of 8 el
            int row  = idx >> 2;              // 0..127
            int col  = (idx & 3) * 8;         // 0,8,16,24
            const bf16* ga = A + (size_t)(mBase + row) * K + kb + col;
            const bf16* gb = W + (size_t)(nBase + row) * K + kb + col;
            char* la = (char*)As + (i * 256 + w * 64) * 16;  // wave-uniform
            char* lb = (char*)Bs + (i * 256 + w * 64) * 16;
            gl_lds16(ga, la);
            gl_lds16(gb, lb);
        }
        __syncthreads();

        bf16x8 af[4], bfv[4];
#pragma unroll
        for (int f = 0; f < 4; f++) {
            int rowA = wm + f * 16 + lm;
            af[f] = *(const bf16x8*)&As[rowA * 32 + lq * 8];
            int rowB = wn + f * 16 + lm;
            bfv[f] = *(const bf16x8*)&Bs[rowB * 32 + lq * 8];
        }
#pragma unroll
        for (int fm = 0; fm < 4; fm++)
#pragma unroll
            for (int fn = 0; fn < 4; fn++)
                acc[fm][fn] = __builtin_amdgcn_mfma_f32_16x16x32_bf16(
                    af[fm], bfv[fn], acc[fm][fn], 0, 0, 0);
    }

    // Epilogue. C layout: row=(lane>>4)*4+r, col=lane&15.
#pragma unroll
    for (int fn = 0; fn < 4; fn++) {
        int n = nBase + wn + fn * 16 + lm;
        float bv = bias[n];
#pragma unroll
        for (int fm = 0; fm < 4; fm++) {
            int m0 = mBase + wm + fm * 16 + lq * 4;
#pragma unroll
            for (int r = 0; r < 4; r++) {
                int m = m0 + r;
                float v = acc[fm][fn][r] + bv;
                if (MODE == 0) {
                    int b = m >> 11, s = m & 2047;
                    int h = n >> 6, d = n & 63;
                    ((bf16*)Ov)[(((size_t)(b * NH + h)) * SS + s) * HD + d] =
                        (bf16)v;
                } else {
                    ((float*)Ov)[(size_t)m * EMBD + n] = v;
                }
            }
        }
    }
}

__global__ __launch_bounds__(256, 2) void gemm_qkv(
    const bf16* __restrict__ xq, const bf16* __restrict__ xk,
    const bf16* __restrict__ xv, const bf16* __restrict__ Wq,
    const bf16* __restrict__ Wk, const bf16* __restrict__ Wv,
    const float* __restrict__ bq, const float* __restrict__ bk,
    const float* __restrict__ bv, bf16* __restrict__ Qo,
    bf16* __restrict__ Ko, bf16* __restrict__ Vo) {
    const int z = blockIdx.z;
    const bf16* A     = (z == 0) ? xq : (z == 1) ? xk : xv;
    const bf16* W     = (z == 0) ? Wq : (z == 1) ? Wk : Wv;
    const float* bias = (z == 0) ? bq : (z == 1) ? bk : bv;
    bf16* O           = (z == 0) ? Qo : (z == 1) ? Ko : Vo;
    gemm_body<0>(A, W, bias, O, blockIdx.y * 128, blockIdx.x * 128);
}

__global__ __launch_bounds__(256, 2) void gemm_out(
    const bf16* __restrict__ A, const bf16* __restrict__ W,
    const float* __restrict__ bias, float* __restrict__ O) {
    gemm_body<1>(A, W, bias, O, blockIdx.y * 128, blockIdx.x * 128);
}

// ---------------------------------------------------------------------------
// Flash attention. Q,K,V in [B,H,S,D] bf16 (workspace). Out: [B,S,EMB] bf16.
// Block: 256 thr (4 waves), 64 q-rows/block (16 per wave), k-tiles of 64.
// Fully synchronous staging — correctness-first.
// ---------------------------------------------------------------------------
__global__ __launch_bounds__(256, 2) void attn_fwd(
    const bf16* __restrict__ Qg, const bf16* __restrict__ Kg,
    const bf16* __restrict__ Vg, bf16* __restrict__ Oatt) {
    __shared__ __align__(16) bf16 Ks[64 * 72];       // [key][d], padded +8
    __shared__ __align__(16) bf16 VT[64 * 72];       // [d][key], padded +8
    __shared__ __align__(16) bf16 Ps[4][16 * 72];    // per-wave P, padded +8

    const int t = threadIdx.x;
    const int l = t & 63, w = t >> 6;
    const int lm = l & 15, lq = l >> 4;
    const int qt = blockIdx.x;                 // q-tile (64 rows)
    const int bh = blockIdx.y;                 // b*NH + h
    const size_t headBase = (size_t)bh * SS * HD;

    // Q A-frags: A[m=lane&15][k=(lane>>4)*8+j], two k-steps of 32 over D=64
    bf16x8 qa0, qa1;
    {
        const bf16* qp =
            Qg + headBase + (size_t)(qt * 64 + w * 16 + lm) * HD + lq * 8;
        qa0 = *(const bf16x8*)qp;
        qa1 = *(const bf16x8*)(qp + 32);
    }

    const floatx4 zero = {0.f, 0.f, 0.f, 0.f};
    float mrow[4], lrow[4];
    floatx4 od[4];
#pragma unroll
    for (int r = 0; r < 4; r++) { mrow[r] = NEG_BIG; lrow[r] = 0.f; }
#pragma unroll
    for (int dt = 0; dt < 4; dt++) od[dt] = zero;

    const int q0 = qt * 64 + w * 16 + lq * 4;  // this lane's first q row

    for (int kt = 0; kt <= qt; ++kt) {
        __syncthreads();
        // Stage K tile [64][64] -> Ks[key][d] (padded stride 72), and
        // V tile transposed -> VT[d][key]. Plain loads + LDS stores.
#pragma unroll
        for (int i = 0; i < 2; i++) {
            int idx = i * 256 + t;         // 0..511
            int row = idx >> 3;            // key in tile, 0..63
            int col = (idx & 7) * 8;       // d base, 0..56
            bf16x8 kv = *(const bf16x8*)(Kg + headBase +
                                         (size_t)(kt * 64 + row) * HD + col);
            *(bf16x8*)&Ks[row * 72 + col] = kv;
            bf16x8 vv = *(const bf16x8*)(Vg + headBase +
                                         (size_t)(kt * 64 + row) * HD + col);
#pragma unroll
            for (int j = 0; j < 8; j++) VT[(col + j) * 72 + row] = vv[j];
        }
        __syncthreads();

        // Scores: S[16q x 64k] = Q * K^T  (4 n-tiles of 16 keys)
        floatx4 sc[4];
#pragma unroll
        for (int j = 0; j < 4; j++) {
            int rowK = j * 16 + lm;
            bf16x8 k0 = *(const bf16x8*)&Ks[rowK * 72 + lq * 8];
            bf16x8 k1 = *(const bf16x8*)&Ks[rowK * 72 + 32 + lq * 8];
            floatx4 z = zero;
            z = __builtin_amdgcn_mfma_f32_16x16x32_bf16(qa0, k0, z, 0, 0, 0);
            z = __builtin_amdgcn_mfma_f32_16x16x32_bf16(qa1, k1, z, 0, 0, 0);
            sc[j] = z;
        }
        // Scale + causal mask (only diagonal tile can mask). Finite sentinel.
#pragma unroll
        for (int j = 0; j < 4; j++)
#pragma unroll
            for (int r = 0; r < 4; r++) {
                float v = sc[j][r] * SCALE;
                if (kt == qt) {
                    int key = kt * 64 + j * 16 + lm;
                    if (key > q0 + r) v = NEG_BIG;
                }
                sc[j][r] = v;
            }
        // Online softmax per q-row (row lives across 16 lanes of group lq)
        float alpha[4];
#pragma unroll
        for (int r = 0; r < 4; r++) {
            float rm = fmaxf(fmaxf(sc[0][r], sc[1][r]),
                             fmaxf(sc[2][r], sc[3][r]));
            rm = fmaxf(rm, __shfl_xor(rm, 1));
            rm = fmaxf(rm, __shfl_xor(rm, 2));
            rm = fmaxf(rm, __shfl_xor(rm, 4));
            rm = fmaxf(rm, __shfl_xor(rm, 8));
            float mnew = fmaxf(mrow[r], rm);
            alpha[r] = __expf(mrow[r] - mnew);   // finite-finite: no NaN
            mrow[r] = mnew;
            float ps = 0.f;
#pragma unroll
            for (int j = 0; j < 4; j++) {
                float p = __expf(sc[j][r] - mnew);
                sc[j][r] = p;
                ps += p;
            }
            ps += __shfl_xor(ps, 1);
            ps += __shfl_xor(ps, 2);
            ps += __shfl_xor(ps, 4);
            ps += __shfl_xor(ps, 8);
            lrow[r] = lrow[r] * alpha[r] + ps;
        }
        // P -> per-wave LDS (C-layout -> A-layout round trip)
#pragma unroll
        for (int j = 0; j < 4; j++)
#pragma unroll
            for (int r = 0; r < 4; r++)
                Ps[w][(lq * 4 + r) * 72 + j * 16 + lm] = (bf16)sc[j][r];
        // Rescale O accumulator
#pragma unroll
        for (int dt = 0; dt < 4; dt++)
#pragma unroll
            for (int r = 0; r < 4; r++) od[dt][r] *= alpha[r];
        // PV: O += P * V   (A from Ps, B from VT — both contiguous b128)
        bf16x8 pa0 = *(const bf16x8*)&Ps[w][lm * 72 + lq * 8];
        bf16x8 pa1 = *(const bf16x8*)&Ps[w][lm * 72 + 32 + lq * 8];
#pragma unroll
        for (int dt = 0; dt < 4; dt++) {
            int rowD = dt * 16 + lm;
            bf16x8 v0 = *(const bf16x8*)&VT[rowD * 72 + lq * 8];
            bf16x8 v1 = *(const bf16x8*)&VT[rowD * 72 + 32 + lq * 8];
            od[dt] =
                __builtin_amdgcn_mfma_f32_16x16x32_bf16(pa0, v0, od[dt], 0, 0, 0);
            od[dt] =
                __builtin_amdgcn_mfma_f32_16x16x32_bf16(pa1, v1, od[dt], 0, 0, 0);
        }
    }

    // Output: [B,S,EMB] bf16 workspace, e = h*64 + d
    const int b = bh >> 4, h = bh & 15;
#pragma unroll
    for (int dt = 0; dt < 4; dt++)
#pragma unroll
        for (int r = 0; r < 4; r++) {
            int s = qt * 64 + w * 16 + lq * 4 + r;
            float v = od[dt][r] / lrow[r];
            Oatt[((size_t)(b * SS + s)) * EMBD + h * HD + dt * 16 + lm] =
                (bf16)v;
        }
}

// ---------------------------------------------------------------------------
extern "C" void kernel_launch(void* const* d_in, const int* in_sizes, int n_in,
                              void* d_out, int out_size, void* d_ws,
                              size_t ws_size, hipStream_t stream) {
    // All float tensors are fp32 per the reference.
    const float* xq = (const float*)d_in[0];
    const float* xk = (const float*)d_in[1];
    const float* xv = (const float*)d_in[2];
    // d_in[3] = causal mask (int32 tril) — causality is hard-coded
    const float* Wq = (const float*)d_in[4];
    const float* bq = (const float*)d_in[5];
    const float* Wk = (const float*)d_in[6];
    const float* bk = (const float*)d_in[7];
    const float* Wv = (const float*)d_in[8];
    const float* bv = (const float*)d_in[9];
    const float* Wo = (const float*)d_in[10];
    const float* bo = (const float*)d_in[11];
    float* out = (float*)d_out;

    const size_t NX = (size_t)BB * SS * EMBD;  // 4 Mi elements
    const size_t NW = (size_t)EMBD * EMBD;     // 1 Mi elements
    bf16* Qw  = (bf16*)d_ws;        // [B,H,S,D]
    bf16* Kw  = Qw + NX;
    bf16* Vw  = Kw + NX;
    bf16* Aw  = Vw + NX;            // attention output [B,S,E]
    bf16* xqb = Aw + NX;            // bf16 input copies
    bf16* xkb = xqb + NX;
    bf16* xvb = xkb + NX;
    bf16* Wqb = xvb + NX;           // bf16 weight copies
    bf16* Wkb = Wqb + NW;
    bf16* Wvb = Wkb + NW;
    bf16* Wob = Wvb + NW;           // total 64 MiB

    // 1) fp32 -> bf16 for x and W tensors
    cvt_all<<<dim3(1024, 7), 256, 0, stream>>>(xq, xk, xv, Wq, Wk, Wv, Wo,
                                               xqb, xkb, xvb, Wqb, Wkb, Wvb,
                                               Wob);
    // 2) QKV projections (fused in z): [B,S,E] @ W^T -> [B,H,S,D]
    gemm_qkv<<<dim3(8, 32, 3), 256, 0, stream>>>(xqb, xkb, xvb, Wqb, Wkb, Wvb,
                                                 bq, bk, bv, Qw, Kw, Vw);
    // 3) Causal flash attention -> [B,S,E] bf16
    attn_fwd<<<dim3(SS / 64, BB * NH), 256, 0, stream>>>(Qw, Kw, Vw, Aw);
    // 4) Output projection -> fp32 d_out
    gemm_out<<<dim3(8, 32), 256, 0, stream>>>(Aw, Wob, bo, out);
}

// Round 4
// 249.791 us; speedup vs baseline: 1.4082x; 1.4082x over previous
//
#include <hip/hip_runtime.h>
#include <hip/hip_bf16.h>

// Problem: B=2, S=2048, EMB=1024, H=16, D=64.
// Harness I/O dtype: fp32. Convert once to bf16, bf16 MFMA pipeline,
// fp32 output. V is produced pre-transposed ([B,H,D,S]) by the QKV GEMM so
// the attention kernel needs no LDS transpose scatter.
#define BB   2
#define SS   2048
#define EMBD 1024
#define NH   16
#define HD   64
#define SCALE 0.125f     // 1/sqrt(64)
#define NEG_BIG (-1e30f) // finite "-inf" sentinel: exp paths can never make NaN

typedef __bf16 bf16;
typedef float  floatx4 __attribute__((ext_vector_type(4)));
typedef __bf16 bf16x4  __attribute__((ext_vector_type(4)));
typedef __bf16 bf16x8  __attribute__((ext_vector_type(8)));

typedef const __attribute__((address_space(1))) void* gas_ptr;
typedef __attribute__((address_space(3))) void*       las_ptr;

// async global->LDS, 16B per lane; LDS dest = wave-uniform base + lane*16
__device__ __forceinline__ void gl_lds16(const void* g, void* l) {
    __builtin_amdgcn_global_load_lds((gas_ptr)g, (las_ptr)l, 16, 0, 0);
}

// ---------------------------------------------------------------------------
// fp32 -> bf16 conversion for x tensors (4Mi els each) and W matrices (1Mi).
// ---------------------------------------------------------------------------
__global__ __launch_bounds__(256) void cvt_all(
    const float* __restrict__ xq, const float* __restrict__ xk,
    const float* __restrict__ xv, const float* __restrict__ Wq,
    const float* __restrict__ Wk, const float* __restrict__ Wv,
    const float* __restrict__ Wo, bf16* __restrict__ xqo,
    bf16* __restrict__ xko, bf16* __restrict__ xvo, bf16* __restrict__ Wqo,
    bf16* __restrict__ Wko, bf16* __restrict__ Wvo, bf16* __restrict__ Woo) {
    const int y = blockIdx.y;
    const float* src;
    bf16* dst;
    size_t n;
    const size_t NX = (size_t)BB * SS * EMBD;    // 4 Mi
    const size_t NW = (size_t)EMBD * EMBD;       // 1 Mi
    switch (y) {
        case 0: src = xq; dst = xqo; n = NX; break;
        case 1: src = xk; dst = xko; n = NX; break;
        case 2: src = xv; dst = xvo; n = NX; break;
        case 3: src = Wq; dst = Wqo; n = NW; break;
        case 4: src = Wk; dst = Wko; n = NW; break;
        case 5: src = Wv; dst = Wvo; n = NW; break;
        default: src = Wo; dst = Woo; n = NW; break;
    }
    const size_t stride = (size_t)gridDim.x * blockDim.x * 4;
    for (size_t i = ((size_t)blockIdx.x * blockDim.x + threadIdx.x) * 4;
         i < n; i += stride) {
        floatx4 v = *(const floatx4*)(src + i);
        bf16x4 o = {(bf16)v[0], (bf16)v[1], (bf16)v[2], (bf16)v[3]};
        *(bf16x4*)(dst + i) = o;
    }
}

// ---------------------------------------------------------------------------
// GEMM: out[m][n] = sum_k A[m][k] * W[n][k] + bias[n]      (x @ W.T + b)
// M=4096, N=1024, K=1024. 128x128 tile, BK=32, 4 waves, 4x4 16x16x32 frags.
// MODE 0: scatter bf16 to [B,H,S,D] (Q,K).
// MODE 1: fp32 linear [M][N] (output projection).
// MODE 2: scatter bf16 to [B,H,D,S] (V transposed). Computed as C^T by
//         swapping MFMA operands (A/B register layouts are identical), so
//         stores stay coalesced along the s-dim.
// ---------------------------------------------------------------------------
template <int MODE>
__device__ __forceinline__ void gemm_body(const bf16* __restrict__ A,
                                          const bf16* __restrict__ W,
                                          const float* __restrict__ bias,
                                          void* __restrict__ Ov,
                                          int mBase, int nBase) {
    __shared__ __align__(16) bf16 As[128 * 32];
    __shared__ __align__(16) bf16 Bs[128 * 32];

    const int t = threadIdx.x;
    const int l = t & 63, w = t >> 6;
    const int lm = l & 15, lq = l >> 4;
    const int K = 1024;
    const int wm = (w >> 1) * 64, wn = (w & 1) * 64;

    const floatx4 zero = {0.f, 0.f, 0.f, 0.f};
    floatx4 acc[4][4];
#pragma unroll
    for (int i = 0; i < 4; i++)
#pragma unroll
        for (int j = 0; j < 4; j++) acc[i][j] = zero;

    for (int kb = 0; kb < K; kb += 32) {
        __syncthreads();
        // m97-exact staging: contiguous, unswizzled, global_load_lds w=16.
#pragma unroll
        for (int i = 0; i < 2; i++) {
            int idx  = i * 256 + t;           // 0..511 lane-chunks of 8 el
            int row  = idx >> 2;              // 0..127
            int col  = (idx & 3) * 8;         // 0,8,16,24
            const bf16* ga = A + (size_t)(mBase + row) * K + kb + col;
            const bf16* gb = W + (size_t)(nBase + row) * K + kb + col;
            char* la = (char*)As + (i * 256 + w * 64) * 16;  // wave-uniform
            char* lb = (char*)Bs + (i * 256 + w * 64) * 16;
            gl_lds16(ga, la);
            gl_lds16(gb, lb);
        }
        __syncthreads();

        bf16x8 af[4], bfv[4];
#pragma unroll
        for (int f = 0; f < 4; f++) {
            int rowA = wm + f * 16 + lm;
            af[f] = *(const bf16x8*)&As[rowA * 32 + lq * 8];
            int rowB = wn + f * 16 + lm;
            bfv[f] = *(const bf16x8*)&Bs[rowB * 32 + lq * 8];
        }
        if (MODE == 2) {
            // C^T: A-operand = W rows, B-operand = x rows
#pragma unroll
            for (int i = 0; i < 4; i++)
#pragma unroll
                for (int j = 0; j < 4; j++)
                    acc[i][j] = __builtin_amdgcn_mfma_f32_16x16x32_bf16(
                        bfv[i], af[j], acc[i][j], 0, 0, 0);
        } else {
#pragma unroll
            for (int fm = 0; fm < 4; fm++)
#pragma unroll
                for (int fn = 0; fn < 4; fn++)
                    acc[fm][fn] = __builtin_amdgcn_mfma_f32_16x16x32_bf16(
                        af[fm], bfv[fn], acc[fm][fn], 0, 0, 0);
        }
    }

    // Epilogue. C layout: row=(lane>>4)*4+r, col=lane&15.
    if (MODE == 2) {
#pragma unroll
        for (int i = 0; i < 4; i++)
#pragma unroll
            for (int j = 0; j < 4; j++) {
                int m = mBase + wm + j * 16 + lm;        // s-dim (col)
                int b = m >> 11, s = m & 2047;
#pragma unroll
                for (int r = 0; r < 4; r++) {
                    int n = nBase + wn + i * 16 + lq * 4 + r;  // d-dim (row)
                    int h = n >> 6, d = n & 63;
                    float v = acc[i][j][r] + bias[n];
                    ((bf16*)Ov)[((size_t)(b * NH + h) * HD + d) * SS + s] =
                        (bf16)v;
                }
            }
    } else {
#pragma unroll
        for (int fn = 0; fn < 4; fn++) {
            int n = nBase + wn + fn * 16 + lm;
            float bv = bias[n];
#pragma unroll
            for (int fm = 0; fm < 4; fm++) {
                int m0 = mBase + wm + fm * 16 + lq * 4;
#pragma unroll
                for (int r = 0; r < 4; r++) {
                    int m = m0 + r;
                    float v = acc[fm][fn][r] + bv;
                    if (MODE == 0) {
                        int b = m >> 11, s = m & 2047;
                        int h = n >> 6, d = n & 63;
                        ((bf16*)Ov)[(((size_t)(b * NH + h)) * SS + s) * HD +
                                    d] = (bf16)v;
                    } else {
                        ((float*)Ov)[(size_t)m * EMBD + n] = v;
                    }
                }
            }
        }
    }
}

__global__ __launch_bounds__(256, 2) void gemm_qkv(
    const bf16* __restrict__ xq, const bf16* __restrict__ xk,
    const bf16* __restrict__ xv, const bf16* __restrict__ Wq,
    const bf16* __restrict__ Wk, const bf16* __restrict__ Wv,
    const float* __restrict__ bq, const float* __restrict__ bk,
    const float* __restrict__ bv, bf16* __restrict__ Qo,
    bf16* __restrict__ Ko, bf16* __restrict__ Vo) {
    const int z = blockIdx.z;
    if (z == 0)
        gemm_body<0>(xq, Wq, bq, Qo, blockIdx.y * 128, blockIdx.x * 128);
    else if (z == 1)
        gemm_body<0>(xk, Wk, bk, Ko, blockIdx.y * 128, blockIdx.x * 128);
    else
        gemm_body<2>(xv, Wv, bv, Vo, blockIdx.y * 128, blockIdx.x * 128);
}

__global__ __launch_bounds__(256, 2) void gemm_out(
    const bf16* __restrict__ A, const bf16* __restrict__ W,
    const float* __restrict__ bias, float* __restrict__ O) {
    gemm_body<1>(A, W, bias, O, blockIdx.y * 128, blockIdx.x * 128);
}

// ---------------------------------------------------------------------------
// Flash attention. Q,K in [B,H,S,D] bf16; V^T in [B,H,D,S] bf16.
// Out: [B,S,EMB] bf16. Block: 256 thr (4 waves), 64 q-rows (16/wave),
// k-tiles of 64. Scores computed TRANSPOSED (S^T = K*Q^T) so each lane owns
// one q-row -> softmax needs only 2 shuffles; P round-trip is 4x b64
// conflict-free; V^T is staged directly (no scatter).
// ---------------------------------------------------------------------------
__global__ __launch_bounds__(256, 2) void attn_fwd(
    const bf16* __restrict__ Qg, const bf16* __restrict__ Kg,
    const bf16* __restrict__ Vtg, bf16* __restrict__ Oatt) {
    __shared__ __align__(16) bf16 Ks[64 * 72];       // [key][d], padded
    __shared__ __align__(16) bf16 VT[64 * 72];       // [d][key], padded
    __shared__ __align__(16) bf16 Ps[4][16 * 72];    // per-wave P [q][key]

    const int t = threadIdx.x;
    const int l = t & 63, w = t >> 6;
    const int lm = l & 15, lq = l >> 4;
    // diagonal swizzle: balances causal work across CUs
    const int qt = (blockIdx.x + blockIdx.y) & 31;
    const int bh = blockIdx.y;                 // b*NH + h
    const size_t kbase = (size_t)bh * SS * HD; // Q,K: [key][d]
    const size_t vbase = (size_t)bh * HD * SS; // V^T: [d][key]

    // Q frags: lane holds Q[q=lm][d=lq*8+j] — serves as MFMA B-operand.
    bf16x8 qa0, qa1;
    {
        const bf16* qp =
            Qg + kbase + (size_t)(qt * 64 + w * 16 + lm) * HD + lq * 8;
        qa0 = *(const bf16x8*)qp;
        qa1 = *(const bf16x8*)(qp + 32);
    }

    const floatx4 zero = {0.f, 0.f, 0.f, 0.f};
    float m_i = NEG_BIG, l_i = 0.f;            // stats for q = lm (this wave)
    floatx4 od[4];
#pragma unroll
    for (int dt = 0; dt < 4; dt++) od[dt] = zero;

    const int qglob = qt * 64 + w * 16 + lm;   // this lane's q-row

    for (int kt = 0; kt <= qt; ++kt) {
        __syncthreads();
        // Stage K [key][d] and V^T [d][key], both b128 contiguous.
#pragma unroll
        for (int i = 0; i < 2; i++) {
            int idx = i * 256 + t;         // 0..511
            int row = idx >> 3;            // 0..63
            int col = (idx & 7) * 8;       // 0..56
            *(bf16x8*)&Ks[row * 72 + col] = *(const bf16x8*)(
                Kg + kbase + (size_t)(kt * 64 + row) * HD + col);
            *(bf16x8*)&VT[row * 72 + col] = *(const bf16x8*)(
                Vtg + vbase + (size_t)row * SS + kt * 64 + col);
        }
        __syncthreads();

        // S^T[key][q]: A = K rows (16 keys/subtile), B = Q frag.
        floatx4 sc[4];
#pragma unroll
        for (int j0 = 0; j0 < 4; j0++) {
            int rowK = j0 * 16 + lm;
            bf16x8 k0 = *(const bf16x8*)&Ks[rowK * 72 + lq * 8];
            bf16x8 k1 = *(const bf16x8*)&Ks[rowK * 72 + 32 + lq * 8];
            floatx4 z = zero;
            z = __builtin_amdgcn_mfma_f32_16x16x32_bf16(k0, qa0, z, 0, 0, 0);
            z = __builtin_amdgcn_mfma_f32_16x16x32_bf16(k1, qa1, z, 0, 0, 0);
            sc[j0] = z;  // C: row=key=j0*16+lq*4+r, col=q=lm
        }
        // Scale + causal mask (diagonal tile only).
#pragma unroll
        for (int j0 = 0; j0 < 4; j0++)
#pragma unroll
            for (int r = 0; r < 4; r++) {
                float v = sc[j0][r] * SCALE;
                if (kt == qt) {
                    int key = kt * 64 + j0 * 16 + lq * 4 + r;
                    if (key > qglob) v = NEG_BIG;
                }
                sc[j0][r] = v;
            }
        // Online softmax: all 16 regs belong to q = lm.
        float mt = sc[0][0];
#pragma unroll
        for (int j0 = 0; j0 < 4; j0++)
#pragma unroll
            for (int r = 0; r < 4; r++) mt = fmaxf(mt, sc[j0][r]);
        mt = fmaxf(mt, __shfl_xor(mt, 16));
        mt = fmaxf(mt, __shfl_xor(mt, 32));
        float mnew = fmaxf(m_i, mt);
        float alpha = __expf(m_i - mnew);
        m_i = mnew;
        float ps = 0.f;
#pragma unroll
        for (int j0 = 0; j0 < 4; j0++)
#pragma unroll
            for (int r = 0; r < 4; r++) {
                float p = __expf(sc[j0][r] - mnew);
                sc[j0][r] = p;
                ps += p;
            }
        ps += __shfl_xor(ps, 16);
        ps += __shfl_xor(ps, 32);
        l_i = l_i * alpha + ps;
        // P -> per-wave LDS: lane's 4 keys are consecutive -> b64 writes.
#pragma unroll
        for (int j0 = 0; j0 < 4; j0++) {
            bf16x4 pk = {(bf16)sc[j0][0], (bf16)sc[j0][1], (bf16)sc[j0][2],
                         (bf16)sc[j0][3]};
            *(bf16x4*)&Ps[w][lm * 72 + j0 * 16 + lq * 4] = pk;
        }
        // Rescale O accumulator: alpha for od-row q=lq*4+r lives at lane q.
        float a0 = __shfl(alpha, lq * 4 + 0);
        float a1 = __shfl(alpha, lq * 4 + 1);
        float a2 = __shfl(alpha, lq * 4 + 2);
        float a3 = __shfl(alpha, lq * 4 + 3);
#pragma unroll
        for (int dt = 0; dt < 4; dt++) {
            od[dt][0] *= a0;
            od[dt][1] *= a1;
            od[dt][2] *= a2;
            od[dt][3] *= a3;
        }
        // PV: O[q][d] += P[q][key] * V[key][d]; A = P (A-layout), B = V^T.
        bf16x8 pa0 = *(const bf16x8*)&Ps[w][lm * 72 + lq * 8];
        bf16x8 pa1 = *(const bf16x8*)&Ps[w][lm * 72 + 32 + lq * 8];
#pragma unroll
        for (int dt = 0; dt < 4; dt++) {
            int rowD = dt * 16 + lm;
            bf16x8 v0 = *(const bf16x8*)&VT[rowD * 72 + lq * 8];
            bf16x8 v1 = *(const bf16x8*)&VT[rowD * 72 + 32 + lq * 8];
            od[dt] =
                __builtin_amdgcn_mfma_f32_16x16x32_bf16(pa0, v0, od[dt], 0, 0, 0);
            od[dt] =
                __builtin_amdgcn_mfma_f32_16x16x32_bf16(pa1, v1, od[dt], 0, 0, 0);
        }
    }

    // Output: [B,S,EMB] bf16 workspace. od row=q=lq*4+r, col=d=dt*16+lm.
    const int b = bh >> 4, h = bh & 15;
    float lr0 = __shfl(l_i, lq * 4 + 0);
    float lr1 = __shfl(l_i, lq * 4 + 1);
    float lr2 = __shfl(l_i, lq * 4 + 2);
    float lr3 = __shfl(l_i, lq * 4 + 3);
#pragma unroll
    for (int dt = 0; dt < 4; dt++) {
        float lr[4] = {lr0, lr1, lr2, lr3};
#pragma unroll
        for (int r = 0; r < 4; r++) {
            int s = qt * 64 + w * 16 + lq * 4 + r;
            float v = od[dt][r] / lr[r];
            Oatt[((size_t)(b * SS + s)) * EMBD + h * HD + dt * 16 + lm] =
                (bf16)v;
        }
    }
}

// ---------------------------------------------------------------------------
extern "C" void kernel_launch(void* const* d_in, const int* in_sizes, int n_in,
                              void* d_out, int out_size, void* d_ws,
                              size_t ws_size, hipStream_t stream) {
    const float* xq = (const float*)d_in[0];
    const float* xk = (const float*)d_in[1];
    const float* xv = (const float*)d_in[2];
    // d_in[3] = causal mask (int32 tril) — causality is hard-coded
    const float* Wq = (const float*)d_in[4];
    const float* bq = (const float*)d_in[5];
    const float* Wk = (const float*)d_in[6];
    const float* bk = (const float*)d_in[7];
    const float* Wv = (const float*)d_in[8];
    const float* bv = (const float*)d_in[9];
    const float* Wo = (const float*)d_in[10];
    const float* bo = (const float*)d_in[11];
    float* out = (float*)d_out;

    const size_t NX = (size_t)BB * SS * EMBD;  // 4 Mi elements
    const size_t NW = (size_t)EMBD * EMBD;     // 1 Mi elements
    bf16* Qw  = (bf16*)d_ws;        // [B,H,S,D]
    bf16* Kw  = Qw + NX;            // [B,H,S,D]
    bf16* Vw  = Kw + NX;            // [B,H,D,S]  (transposed)
    bf16* Aw  = Vw + NX;            // attention output [B,S,E]
    bf16* xqb = Aw + NX;            // bf16 input copies
    bf16* xkb = xqb + NX;
    bf16* xvb = xkb + NX;
    bf16* Wqb = xvb + NX;           // bf16 weight copies
    bf16* Wkb = Wqb + NW;
    bf16* Wvb = Wkb + NW;
    bf16* Wob = Wvb + NW;           // total 64 MiB

    cvt_all<<<dim3(1024, 7), 256, 0, stream>>>(xq, xk, xv, Wq, Wk, Wv, Wo,
                                               xqb, xkb, xvb, Wqb, Wkb, Wvb,
                                               Wob);
    gemm_qkv<<<dim3(8, 32, 3), 256, 0, stream>>>(xqb, xkb, xvb, Wqb, Wkb, Wvb,
                                                 bq, bk, bv, Qw, Kw, Vw);
    attn_fwd<<<dim3(SS / 64, BB * NH), 256, 0, stream>>>(Qw, Kw, Vw, Aw);
    gemm_out<<<dim3(8, 32), 256, 0, stream>>>(Aw, Wob, bo, out);
}

// Round 5
// 240.166 us; speedup vs baseline: 1.4646x; 1.0401x over previous
//
#include <hip/hip_runtime.h>
#include <hip/hip_bf16.h>

// Problem: B=2, S=2048, EMB=1024, H=16, D=64.
// Harness I/O dtype: fp32. Convert once to bf16, bf16 MFMA pipeline,
// fp32 output. V is produced pre-transposed ([B,H,D,S]) by the QKV GEMM.
#define BB   2
#define SS   2048
#define EMBD 1024
#define NH   16
#define HD   64
#define SCALE 0.125f     // 1/sqrt(64)
#define NEG_BIG (-1e30f) // finite "-inf" sentinel: exp paths can never make NaN

typedef __bf16 bf16;
typedef float  floatx4 __attribute__((ext_vector_type(4)));
typedef __bf16 bf16x4  __attribute__((ext_vector_type(4)));
typedef __bf16 bf16x8  __attribute__((ext_vector_type(8)));

typedef const __attribute__((address_space(1))) void* gas_ptr;
typedef __attribute__((address_space(3))) void*       las_ptr;

// async global->LDS, 16B per lane; LDS dest = wave-uniform base + lane*16
__device__ __forceinline__ void gl_lds16(const void* g, void* l) {
    __builtin_amdgcn_global_load_lds((gas_ptr)g, (las_ptr)l, 16, 0, 0);
}

// ---------------------------------------------------------------------------
// fp32 -> bf16 conversion for x tensors (4Mi els each) and W matrices (1Mi).
// ---------------------------------------------------------------------------
__global__ __launch_bounds__(256) void cvt_all(
    const float* __restrict__ xq, const float* __restrict__ xk,
    const float* __restrict__ xv, const float* __restrict__ Wq,
    const float* __restrict__ Wk, const float* __restrict__ Wv,
    const float* __restrict__ Wo, bf16* __restrict__ xqo,
    bf16* __restrict__ xko, bf16* __restrict__ xvo, bf16* __restrict__ Wqo,
    bf16* __restrict__ Wko, bf16* __restrict__ Wvo, bf16* __restrict__ Woo) {
    const int y = blockIdx.y;
    const float* src;
    bf16* dst;
    size_t n;
    const size_t NX = (size_t)BB * SS * EMBD;    // 4 Mi
    const size_t NW = (size_t)EMBD * EMBD;       // 1 Mi
    switch (y) {
        case 0: src = xq; dst = xqo; n = NX; break;
        case 1: src = xk; dst = xko; n = NX; break;
        case 2: src = xv; dst = xvo; n = NX; break;
        case 3: src = Wq; dst = Wqo; n = NW; break;
        case 4: src = Wk; dst = Wko; n = NW; break;
        case 5: src = Wv; dst = Wvo; n = NW; break;
        default: src = Wo; dst = Woo; n = NW; break;
    }
    const size_t stride = (size_t)gridDim.x * blockDim.x * 4;
    for (size_t i = ((size_t)blockIdx.x * blockDim.x + threadIdx.x) * 4;
         i < n; i += stride) {
        floatx4 v = *(const floatx4*)(src + i);
        bf16x4 o = {(bf16)v[0], (bf16)v[1], (bf16)v[2], (bf16)v[3]};
        *(bf16x4*)(dst + i) = o;
    }
}

// ---------------------------------------------------------------------------
// GEMM: out[m][n] = sum_k A[m][k] * W[n][k] + bias[n]      (x @ W.T + b)
// M=4096, N=1024, K=1024. 128x128 tile, BK=64 staged as TWO packed 128x32
// sub-tiles (keeps the conflict-minimal 64B row stride AND the wave-uniform
// global_load_lds contiguity) -> half the barrier drains of BK=32.
// MODE 0: scatter bf16 to [B,H,S,D] (Q,K).
// MODE 1: fp32 linear [M][N] (output projection).
// MODE 2: scatter bf16 to [B,H,D,S] (V transposed; C^T via swapped operands).
// ---------------------------------------------------------------------------
template <int MODE>
__device__ __forceinline__ void gemm_body(const bf16* __restrict__ A,
                                          const bf16* __restrict__ W,
                                          const float* __restrict__ bias,
                                          void* __restrict__ Ov,
                                          int mBase, int nBase) {
    __shared__ __align__(16) bf16 As[2 * 128 * 32];
    __shared__ __align__(16) bf16 Bs[2 * 128 * 32];

    const int t = threadIdx.x;
    const int l = t & 63, w = t >> 6;
    const int lm = l & 15, lq = l >> 4;
    const int K = 1024;
    const int wm = (w >> 1) * 64, wn = (w & 1) * 64;

    const floatx4 zero = {0.f, 0.f, 0.f, 0.f};
    floatx4 acc[4][4];
#pragma unroll
    for (int i = 0; i < 4; i++)
#pragma unroll
        for (int j = 0; j < 4; j++) acc[i][j] = zero;

    for (int kb = 0; kb < K; kb += 64) {
        __syncthreads();
        // Stage 2 k-halves per tile; each half is a packed 128x32 sub-tile.
#pragma unroll
        for (int i = 0; i < 4; i++) {
            int half = i >> 1;                 // uniform per i
            int rem  = (i & 1) * 256 + t;      // 0..511
            int row  = rem >> 2;               // 0..127
            int col  = half * 32 + (rem & 3) * 8;
            const bf16* ga = A + (size_t)(mBase + row) * K + kb + col;
            const bf16* gb = W + (size_t)(nBase + row) * K + kb + col;
            char* la = (char*)As + (i * 256 + w * 64) * 16;  // wave-uniform
            char* lb = (char*)Bs + (i * 256 + w * 64) * 16;
            gl_lds16(ga, la);
            gl_lds16(gb, lb);
        }
        __syncthreads();

#pragma unroll
        for (int half = 0; half < 2; half++) {
            const bf16* Ah = As + half * 128 * 32;
            const bf16* Bh = Bs + half * 128 * 32;
            bf16x8 af[4], bfv[4];
#pragma unroll
            for (int f = 0; f < 4; f++) {
                int rowA = wm + f * 16 + lm;
                af[f] = *(const bf16x8*)&Ah[rowA * 32 + lq * 8];
                int rowB = wn + f * 16 + lm;
                bfv[f] = *(const bf16x8*)&Bh[rowB * 32 + lq * 8];
            }
            if (MODE == 2) {
#pragma unroll
                for (int i = 0; i < 4; i++)
#pragma unroll
                    for (int j = 0; j < 4; j++)
                        acc[i][j] = __builtin_amdgcn_mfma_f32_16x16x32_bf16(
                            bfv[i], af[j], acc[i][j], 0, 0, 0);
            } else {
#pragma unroll
                for (int fm = 0; fm < 4; fm++)
#pragma unroll
                    for (int fn = 0; fn < 4; fn++)
                        acc[fm][fn] =
                            __builtin_amdgcn_mfma_f32_16x16x32_bf16(
                                af[fm], bfv[fn], acc[fm][fn], 0, 0, 0);
            }
        }
    }

    // Epilogue. C layout: row=(lane>>4)*4+r, col=lane&15.
    if (MODE == 2) {
#pragma unroll
        for (int i = 0; i < 4; i++)
#pragma unroll
            for (int j = 0; j < 4; j++) {
                int m = mBase + wm + j * 16 + lm;        // s-dim (col)
                int b = m >> 11, s = m & 2047;
#pragma unroll
                for (int r = 0; r < 4; r++) {
                    int n = nBase + wn + i * 16 + lq * 4 + r;  // d-dim (row)
                    int h = n >> 6, d = n & 63;
                    float v = acc[i][j][r] + bias[n];
                    ((bf16*)Ov)[((size_t)(b * NH + h) * HD + d) * SS + s] =
                        (bf16)v;
                }
            }
    } else {
#pragma unroll
        for (int fn = 0; fn < 4; fn++) {
            int n = nBase + wn + fn * 16 + lm;
            float bv = bias[n];
#pragma unroll
            for (int fm = 0; fm < 4; fm++) {
                int m0 = mBase + wm + fm * 16 + lq * 4;
#pragma unroll
                for (int r = 0; r < 4; r++) {
                    int m = m0 + r;
                    float v = acc[fm][fn][r] + bv;
                    if (MODE == 0) {
                        int b = m >> 11, s = m & 2047;
                        int h = n >> 6, d = n & 63;
                        ((bf16*)Ov)[(((size_t)(b * NH + h)) * SS + s) * HD +
                                    d] = (bf16)v;
                    } else {
                        ((float*)Ov)[(size_t)m * EMBD + n] = v;
                    }
                }
            }
        }
    }
}

__global__ __launch_bounds__(256, 2) void gemm_qkv(
    const bf16* __restrict__ xq, const bf16* __restrict__ xk,
    const bf16* __restrict__ xv, const bf16* __restrict__ Wq,
    const bf16* __restrict__ Wk, const bf16* __restrict__ Wv,
    const float* __restrict__ bq, const float* __restrict__ bk,
    const float* __restrict__ bv, bf16* __restrict__ Qo,
    bf16* __restrict__ Ko, bf16* __restrict__ Vo) {
    const int z = blockIdx.z;
    if (z == 0)
        gemm_body<0>(xq, Wq, bq, Qo, blockIdx.y * 128, blockIdx.x * 128);
    else if (z == 1)
        gemm_body<0>(xk, Wk, bk, Ko, blockIdx.y * 128, blockIdx.x * 128);
    else
        gemm_body<2>(xv, Wv, bv, Vo, blockIdx.y * 128, blockIdx.x * 128);
}

__global__ __launch_bounds__(256, 2) void gemm_out(
    const bf16* __restrict__ A, const bf16* __restrict__ W,
    const float* __restrict__ bias, float* __restrict__ O) {
    gemm_body<1>(A, W, bias, O, blockIdx.y * 128, blockIdx.x * 128);
}

// ---------------------------------------------------------------------------
// Flash attention. Q,K in [B,H,S,D] bf16; V^T in [B,H,D,S] bf16.
// Out: [B,S,EMB] bf16. Grid 512 blocks = dim3(16, 32): each block runs TWO
// jobs, qt = x and qt = 31-x  -> exactly 33 k-iterations per block (perfect
// causal load balance, no tail). Next K/V tile register-prefetched to hide
// HBM latency. Scores computed transposed (S^T = K*Q^T): lane owns one
// q-row -> 2-shuffle softmax; P round-trip b64; V^T staged directly.
// ---------------------------------------------------------------------------
__global__ __launch_bounds__(256, 2) void attn_fwd(
    const bf16* __restrict__ Qg, const bf16* __restrict__ Kg,
    const bf16* __restrict__ Vtg, bf16* __restrict__ Oatt) {
    __shared__ __align__(16) bf16 Ks[64 * 72];       // [key][d], padded
    __shared__ __align__(16) bf16 VT[64 * 72];       // [d][key], padded
    __shared__ __align__(16) bf16 Ps[4][16 * 72];    // per-wave P [q][key]

    const int t = threadIdx.x;
    const int l = t & 63, w = t >> 6;
    const int lm = l & 15, lq = l >> 4;
    const int bh = blockIdx.y;                 // b*NH + h
    const size_t kbase = (size_t)bh * SS * HD; // Q,K: [key][d]
    const size_t vbase = (size_t)bh * HD * SS; // V^T: [d][key]
    const int b = bh >> 4, h = bh & 15;
    const floatx4 zero = {0.f, 0.f, 0.f, 0.f};

#pragma unroll
    for (int job = 0; job < 2; ++job) {
        const int qt = job ? (31 - blockIdx.x) : blockIdx.x;

        // Q frags: lane holds Q[q=lm][d=lq*8+j] — serves as MFMA B-operand.
        bf16x8 qa0, qa1;
        {
            const bf16* qp =
                Qg + kbase + (size_t)(qt * 64 + w * 16 + lm) * HD + lq * 8;
            qa0 = *(const bf16x8*)qp;
            qa1 = *(const bf16x8*)(qp + 32);
        }

        float m_i = NEG_BIG, l_i = 0.f;        // stats for q = lm (this wave)
        floatx4 od[4];
#pragma unroll
        for (int dt = 0; dt < 4; dt++) od[dt] = zero;

        const int qglob = qt * 64 + w * 16 + lm;   // this lane's q-row

        // Prefetch tile kt=0 into registers.
        bf16x8 kreg[2], vreg[2];
#pragma unroll
        for (int i = 0; i < 2; i++) {
            int idx = i * 256 + t;
            int row = idx >> 3;
            int col = (idx & 7) * 8;
            kreg[i] = *(const bf16x8*)(Kg + kbase + (size_t)row * HD + col);
            vreg[i] = *(const bf16x8*)(Vtg + vbase + (size_t)row * SS + col);
        }

        for (int kt = 0; kt <= qt; ++kt) {
            __syncthreads();
            // Commit prefetched K [key][d] and V^T [d][key] to LDS.
#pragma unroll
            for (int i = 0; i < 2; i++) {
                int idx = i * 256 + t;
                int row = idx >> 3;
                int col = (idx & 7) * 8;
                *(bf16x8*)&Ks[row * 72 + col] = kreg[i];
                *(bf16x8*)&VT[row * 72 + col] = vreg[i];
            }
            __syncthreads();
            // Issue next tile's global loads early (consumed next iter).
            if (kt < qt) {
#pragma unroll
                for (int i = 0; i < 2; i++) {
                    int idx = i * 256 + t;
                    int row = idx >> 3;
                    int col = (idx & 7) * 8;
                    kreg[i] = *(const bf16x8*)(
                        Kg + kbase + (size_t)((kt + 1) * 64 + row) * HD + col);
                    vreg[i] = *(const bf16x8*)(
                        Vtg + vbase + (size_t)row * SS + (kt + 1) * 64 + col);
                }
            }

            // S^T[key][q]: A = K rows (16 keys/subtile), B = Q frag.
            floatx4 sc[4];
#pragma unroll
            for (int j0 = 0; j0 < 4; j0++) {
                int rowK = j0 * 16 + lm;
                bf16x8 k0 = *(const bf16x8*)&Ks[rowK * 72 + lq * 8];
                bf16x8 k1 = *(const bf16x8*)&Ks[rowK * 72 + 32 + lq * 8];
                floatx4 z = zero;
                z = __builtin_amdgcn_mfma_f32_16x16x32_bf16(k0, qa0, z, 0, 0,
                                                            0);
                z = __builtin_amdgcn_mfma_f32_16x16x32_bf16(k1, qa1, z, 0, 0,
                                                            0);
                sc[j0] = z;  // C: row=key=j0*16+lq*4+r, col=q=lm
            }
            // Scale + causal mask (diagonal tile only).
#pragma unroll
            for (int j0 = 0; j0 < 4; j0++)
#pragma unroll
                for (int r = 0; r < 4; r++) {
                    float v = sc[j0][r] * SCALE;
                    if (kt == qt) {
                        int key = kt * 64 + j0 * 16 + lq * 4 + r;
                        if (key > qglob) v = NEG_BIG;
                    }
                    sc[j0][r] = v;
                }
            // Online softmax: all 16 regs belong to q = lm.
            float mt = sc[0][0];
#pragma unroll
            for (int j0 = 0; j0 < 4; j0++)
#pragma unroll
                for (int r = 0; r < 4; r++) mt = fmaxf(mt, sc[j0][r]);
            mt = fmaxf(mt, __shfl_xor(mt, 16));
            mt = fmaxf(mt, __shfl_xor(mt, 32));
            float mnew = fmaxf(m_i, mt);
            float alpha = __expf(m_i - mnew);
            m_i = mnew;
            float ps = 0.f;
#pragma unroll
            for (int j0 = 0; j0 < 4; j0++)
#pragma unroll
                for (int r = 0; r < 4; r++) {
                    float p = __expf(sc[j0][r] - mnew);
                    sc[j0][r] = p;
                    ps += p;
                }
            ps += __shfl_xor(ps, 16);
            ps += __shfl_xor(ps, 32);
            l_i = l_i * alpha + ps;
            // P -> per-wave LDS: lane's 4 keys are consecutive -> b64.
#pragma unroll
            for (int j0 = 0; j0 < 4; j0++) {
                bf16x4 pk = {(bf16)sc[j0][0], (bf16)sc[j0][1],
                             (bf16)sc[j0][2], (bf16)sc[j0][3]};
                *(bf16x4*)&Ps[w][lm * 72 + j0 * 16 + lq * 4] = pk;
            }
            // Rescale O accumulator: alpha for od-row q=lq*4+r at lane q.
            float a0 = __shfl(alpha, lq * 4 + 0);
            float a1 = __shfl(alpha, lq * 4 + 1);
            float a2 = __shfl(alpha, lq * 4 + 2);
            float a3 = __shfl(alpha, lq * 4 + 3);
#pragma unroll
            for (int dt = 0; dt < 4; dt++) {
                od[dt][0] *= a0;
                od[dt][1] *= a1;
                od[dt][2] *= a2;
                od[dt][3] *= a3;
            }
            // PV: O[q][d] += P[q][key] * V[key][d]; A = P, B = V^T.
            bf16x8 pa0 = *(const bf16x8*)&Ps[w][lm * 72 + lq * 8];
            bf16x8 pa1 = *(const bf16x8*)&Ps[w][lm * 72 + 32 + lq * 8];
#pragma unroll
            for (int dt = 0; dt < 4; dt++) {
                int rowD = dt * 16 + lm;
                bf16x8 v0 = *(const bf16x8*)&VT[rowD * 72 + lq * 8];
                bf16x8 v1 = *(const bf16x8*)&VT[rowD * 72 + 32 + lq * 8];
                od[dt] = __builtin_amdgcn_mfma_f32_16x16x32_bf16(pa0, v0,
                                                                 od[dt], 0, 0,
                                                                 0);
                od[dt] = __builtin_amdgcn_mfma_f32_16x16x32_bf16(pa1, v1,
                                                                 od[dt], 0, 0,
                                                                 0);
            }
        }

        // Output: [B,S,EMB] bf16. od row=q=lq*4+r, col=d=dt*16+lm.
        float lr0 = __shfl(l_i, lq * 4 + 0);
        float lr1 = __shfl(l_i, lq * 4 + 1);
        float lr2 = __shfl(l_i, lq * 4 + 2);
        float lr3 = __shfl(l_i, lq * 4 + 3);
        float lr[4] = {lr0, lr1, lr2, lr3};
#pragma unroll
        for (int dt = 0; dt < 4; dt++) {
#pragma unroll
            for (int r = 0; r < 4; r++) {
                int s = qt * 64 + w * 16 + lq * 4 + r;
                float v = od[dt][r] / lr[r];
                Oatt[((size_t)(b * SS + s)) * EMBD + h * HD + dt * 16 + lm] =
                    (bf16)v;
            }
        }
    }
}

// ---------------------------------------------------------------------------
extern "C" void kernel_launch(void* const* d_in, const int* in_sizes, int n_in,
                              void* d_out, int out_size, void* d_ws,
                              size_t ws_size, hipStream_t stream) {
    const float* xq = (const float*)d_in[0];
    const float* xk = (const float*)d_in[1];
    const float* xv = (const float*)d_in[2];
    // d_in[3] = causal mask (int32 tril) — causality is hard-coded
    const float* Wq = (const float*)d_in[4];
    const float* bq = (const float*)d_in[5];
    const float* Wk = (const float*)d_in[6];
    const float* bk = (const float*)d_in[7];
    const float* Wv = (const float*)d_in[8];
    const float* bv = (const float*)d_in[9];
    const float* Wo = (const float*)d_in[10];
    const float* bo = (const float*)d_in[11];
    float* out = (float*)d_out;

    const size_t NX = (size_t)BB * SS * EMBD;  // 4 Mi elements
    const size_t NW = (size_t)EMBD * EMBD;     // 1 Mi elements
    bf16* Qw  = (bf16*)d_ws;        // [B,H,S,D]
    bf16* Kw  = Qw + NX;            // [B,H,S,D]
    bf16* Vw  = Kw + NX;            // [B,H,D,S]  (transposed)
    bf16* Aw  = Vw + NX;            // attention output [B,S,E]
    bf16* xqb = Aw + NX;            // bf16 input copies
    bf16* xkb = xqb + NX;
    bf16* xvb = xkb + NX;
    bf16* Wqb = xvb + NX;           // bf16 weight copies
    bf16* Wkb = Wqb + NW;
    bf16* Wvb = Wkb + NW;
    bf16* Wob = Wvb + NW;           // total 64 MiB

    cvt_all<<<dim3(1024, 7), 256, 0, stream>>>(xq, xk, xv, Wq, Wk, Wv, Wo,
                                               xqb, xkb, xvb, Wqb, Wkb, Wvb,
                                               Wob);
    gemm_qkv<<<dim3(8, 32, 3), 256, 0, stream>>>(xqb, xkb, xvb, Wqb, Wkb, Wvb,
                                                 bq, bk, bv, Qw, Kw, Vw);
    attn_fwd<<<dim3(16, BB * NH), 256, 0, stream>>>(Qw, Kw, Vw, Aw);
    gemm_out<<<dim3(8, 32), 256, 0, stream>>>(Aw, Wob, bo, out);
}